// Round 6
// baseline (3184.505 us; speedup 1.0000x reference)
//
#include <hip/hip_runtime.h>

typedef __bf16 bf16_t;
typedef bf16_t bf16x8 __attribute__((ext_vector_type(8)));
typedef float f32x4 __attribute__((ext_vector_type(4)));
typedef float f32x2 __attribute__((ext_vector_type(2)));
typedef unsigned short u16;

#define P_TOTAL 98304
#define PTS_PER_BATCH 49152

__device__ __forceinline__ u16 f2bs(float f){ bf16_t b=(bf16_t)f; return __builtin_bit_cast(u16,b); }

// ---------- weight transpose: (K,N) fp32 -> (N,K) bf16 ----------
__global__ void k_wtrans15(const float* __restrict__ lz, const float* __restrict__ f0,
                           const float* __restrict__ f1, u16* __restrict__ dst){
  __shared__ float tile[32][33];
  int z = blockIdx.z;
  const float* src = (z<5) ? (lz + (size_t)z*262144)
                   : (z<10 ? (f0 + (size_t)(z-5)*262144)
                           : (f1 + (size_t)(z-10)*262144));
  u16* d = dst + (size_t)z*262144;
  int k0 = blockIdx.x*32, n0 = blockIdx.y*32;
  int t = threadIdx.x, a = t&31, r = t>>5;
  #pragma unroll
  for (int p=0;p<4;p++) tile[r+p*8][a] = src[(size_t)(k0+r+p*8)*512 + n0+a];
  __syncthreads();
  #pragma unroll
  for (int p=0;p<4;p++) d[(size_t)(n0+r+p*8)*512 + k0+a] = f2bs(tile[a][r+p*8]);
}

__global__ void k_wtrans_in(const float* __restrict__ w, u16* __restrict__ dst){
  __shared__ float tile[32][33];
  int k0 = blockIdx.x*32, n0 = blockIdx.y*32;
  int t = threadIdx.x, a = t&31, r = t>>5;
  #pragma unroll
  for (int p=0;p<4;p++){
    int k = k0+r+p*8;
    tile[r+p*8][a] = (k < 63) ? w[(size_t)k*512 + n0+a] : 0.f;
  }
  __syncthreads();
  #pragma unroll
  for (int p=0;p<4;p++) dst[(size_t)(n0+r+p*8)*64 + k0+a] = f2bs(tile[a][r+p*8]);
}

// ---------- feature transpose: (B,512,128,128) f32 -> (B,128,128,512) bf16 ----------
__global__ void k_featT(const float* __restrict__ feat, u16* __restrict__ featT){
  int x = threadIdx.x;
  int c8 = blockIdx.x*8;
  int y = blockIdx.y, b = blockIdx.z;
  float v[8];
  #pragma unroll
  for (int j=0;j<8;j++)
    v[j] = feat[(((size_t)(b*512 + c8 + j))*128 + y)*128 + x];
  bf16x8 o;
  #pragma unroll
  for (int j=0;j<8;j++) o[j] = (bf16_t)v[j];
  *(bf16x8*)(featT + (((size_t)(b*128 + y))*128 + x)*512 + c8) = o;
}

// ---------- per-point: geometry + bilinear + positional encoding ----------
__global__ void k_points(const float* __restrict__ world, const float* __restrict__ c2w,
                         const float* __restrict__ kmat, const u16* __restrict__ featT,
                         u16* __restrict__ alignedB, u16* __restrict__ encB){
  int wid = threadIdx.x >> 6, lane = threadIdx.x & 63;
  int gp = blockIdx.x*4 + wid;
  int b = gp / PTS_PER_BATCH;
  const float* wp = world + (size_t)gp*3;
  float px = wp[0], py = wp[1], pz = wp[2];
  const float* cw = c2w + b*16;
  float dx = px - cw[3], dy = py - cw[7], dz = pz - cw[11];
  float cx = cw[0]*dx + cw[4]*dy + cw[8]*dz;
  float cy = cw[1]*dx + cw[5]*dy + cw[9]*dz;
  float cz = cw[2]*dx + cw[6]*dy + cw[10]*dz;
  const float* km = kmat + b*9;
  float u0 = km[0]*cx + km[1]*cy + km[2]*cz;
  float v0 = km[3]*cx + km[4]*cy + km[5]*cz;
  float zz = km[6]*cx + km[7]*cy + km[8]*cz;
  if (fabsf(zz) < 1e-6f) zz = 1e-6f;
  float uu = u0/zz, vv = v0/zz;
  float xf = fminf(fmaxf(uu, 0.f), 127.f);
  float yf = fminf(fmaxf(vv, 0.f), 127.f);
  float x0f = floorf(xf), y0f = floorf(yf);
  int x0 = (int)x0f, y0 = (int)y0f;
  int x1 = min(x0+1,127), y1 = min(y0+1,127);
  float wx = xf - x0f, wy = yf - y0f;
  float w00 = (1.f-wx)*(1.f-wy), w01 = wx*(1.f-wy), w10 = (1.f-wx)*wy, w11 = wx*wy;
  size_t fb = (size_t)b*128*128*512;
  int c8 = lane*8;
  const bf16x8 t00 = *(const bf16x8*)(featT + fb + (size_t)(y0*128+x0)*512 + c8);
  const bf16x8 t01 = *(const bf16x8*)(featT + fb + (size_t)(y0*128+x1)*512 + c8);
  const bf16x8 t10 = *(const bf16x8*)(featT + fb + (size_t)(y1*128+x0)*512 + c8);
  const bf16x8 t11 = *(const bf16x8*)(featT + fb + (size_t)(y1*128+x1)*512 + c8);
  bf16x8 o;
  #pragma unroll
  for (int j=0;j<8;j++){
    float r = (float)t00[j]*w00 + (float)t01[j]*w01 + (float)t10[j]*w10 + (float)t11[j]*w11;
    o[j] = (bf16_t)r;
  }
  *(bf16x8*)(alignedB + (size_t)gp*512 + c8) = o;
  float cam[3] = {cx, cy, cz};
  float e;
  if (lane < 3) e = cam[lane];
  else if (lane < 33){
    int i = (lane-3)/10, f = (lane-3)%10;
    e = sinf(6.2831855f * cam[i] * (float)(1<<f));
  } else if (lane < 63){
    int i = (lane-33)/10, f = (lane-33)%10;
    e = cosf(6.2831855f * cam[i] * (float)(1<<f));
  } else e = 0.f;
  encB[(size_t)gp*64 + lane] = f2bs(e);
}

// ============ fused persistent MLP (M=64/block, single-acc-file phases) ============
// 512 thr (8 waves, 2/SIMD, 256 reg budget). wave w owns n-strip [w*64,w*64+64);
// h fp32 resident in regs (64, C-layout). Two 64KB swizzled LDS activation buffers.
// fc0 computed in two n-halves (acc[4][2]=32 regs) so h+acc never exceeds 96 regs.
// Weights (N,K) bf16 streamed from global (L2/L3 broadcast), rolled reg dbuf.
// K-loop stays ROLLED (unroll 2 max) — full unroll => spill (round 4).

template<int NK, int NT>
__device__ __forceinline__ void gemm_any(const u16* sA, const u16* __restrict__ Bt, int ldb,
                                         int n_base, int fm, int fk8, f32x4 (&acc)[4][NT]){
  const u16* bp = Bt + (size_t)(n_base + fm)*ldb + fk8*8;
  bf16x8 b[NT];
  #pragma unroll
  for (int nt=0;nt<NT;nt++)
    b[nt] = *(const bf16x8*)(bp + nt*16*ldb);
  #pragma unroll 2
  for (int kt=0; kt<NK-1; ++kt){
    bf16x8 bn[NT];
    #pragma unroll
    for (int nt=0;nt<NT;nt++)
      bn[nt] = *(const bf16x8*)(bp + nt*16*ldb + (kt+1)*32);
    bf16x8 a[4];
    #pragma unroll
    for (int mt=0;mt<4;mt++){
      int m = mt*16 + fm;
      int kc = kt*4 + fk8;
      a[mt] = *(const bf16x8*)&sA[m*512 + ((kc ^ (m&7))<<3)];
    }
    #pragma unroll
    for (int mt=0;mt<4;mt++)
      #pragma unroll
      for (int nt=0;nt<NT;nt++)
        acc[mt][nt] = __builtin_amdgcn_mfma_f32_16x16x32_bf16(a[mt], b[nt], acc[mt][nt], 0,0,0);
    #pragma unroll
    for (int nt=0;nt<NT;nt++) b[nt] = bn[nt];
  }
  {
    bf16x8 a[4];
    #pragma unroll
    for (int mt=0;mt<4;mt++){
      int m = mt*16 + fm;
      int kc = (NK-1)*4 + fk8;
      a[mt] = *(const bf16x8*)&sA[m*512 + ((kc ^ (m&7))<<3)];
    }
    #pragma unroll
    for (int mt=0;mt<4;mt++)
      #pragma unroll
      for (int nt=0;nt<NT;nt++)
        acc[mt][nt] = __builtin_amdgcn_mfma_f32_16x16x32_bf16(a[mt], b[nt], acc[mt][nt], 0,0,0);
  }
}

template<int NT>
__device__ __forceinline__ void add_bias(const float* __restrict__ bias, int n_base, int fm,
                                         f32x4 (&acc)[4][NT]){
  #pragma unroll
  for (int nt=0;nt<NT;nt++){
    float bv = bias[n_base + nt*16 + fm];
    #pragma unroll
    for (int mt=0;mt<4;mt++)
      #pragma unroll
      for (int r=0;r<4;r++) acc[mt][nt][r] += bv;
  }
}

// write relu(acc) bf16 into swizzled LDS cols [n_base, n_base+NT*16)
template<int NT>
__device__ __forceinline__ void write_relu(u16* dst, int l, int n_base, f32x4 (&acc)[4][NT]){
  const int fm = l&15, rq = (l>>4)*4;
  #pragma unroll
  for (int mt=0;mt<4;mt++)
    #pragma unroll
    for (int nt=0;nt<NT;nt++){
      int k = n_base + nt*16 + fm;
      #pragma unroll
      for (int r=0;r<4;r++){
        int m = mt*16 + rq + r;
        dst[m*512 + ((((k>>3) ^ (m&7))<<3) | (k&7))] = f2bs(fmaxf(acc[mt][nt][r], 0.f));
      }
    }
}

// stage 64x512 bf16 row-major global tile -> swizzled LDS (512 threads)
__device__ __forceinline__ void stage_tile(u16* dst, const u16* __restrict__ src, int t){
  int m = t>>3, g = t&7;
  #pragma unroll
  for (int j=0;j<8;j++){
    int kc = g*8 + j;
    *(uint4*)&dst[m*512 + ((kc ^ (m&7))<<3)] =
        *(const uint4*)(src + (size_t)m*512 + kc*8);
  }
}

__global__ __launch_bounds__(512, 2) void k_net(
    const u16* __restrict__ alignedB, const u16* __restrict__ encB,
    const u16* __restrict__ wtin, const float* __restrict__ b_in,
    const u16* __restrict__ wts, const float* __restrict__ bz,
    const float* __restrict__ b0, const float* __restrict__ b1,
    const float* __restrict__ wout, const float* __restrict__ bout,
    float* __restrict__ out)
{
  __shared__ u16 bufA[64*512];   // 64 KB: aligned / relu(h)
  __shared__ u16 bufB[64*512];   // 64 KB: enc / relu(net)
  const int t = threadIdx.x, w = t>>6, l = t&63;
  const int m0 = blockIdx.x*64;
  const int wn = w*64, fm = l&15, fk8 = l>>4;

  // pre-loop: aligned -> bufA, enc -> bufB
  stage_tile(bufA, alignedB + (size_t)m0*512, t);
  if (t < 256){
    int m = t>>2;
    #pragma unroll
    for (int j=0;j<2;j++){
      int kc = (t&3)*2 + j;
      *(uint4*)&bufB[m*512 + ((kc ^ (m&7))<<3)] =
          *(const uint4*)(encB + (size_t)(m0+m)*64 + kc*8);
    }
  }
  __syncthreads();

  f32x4 h[4][4] = {};
  gemm_any<2,4>(bufB, wtin, 64, wn, fm, fk8, h);
  add_bias<4>(b_in, wn, fm, h);

  for (int i=0;i<5;i++){
    // h += aligned @ Wz + bz    (bufA = aligned)
    gemm_any<16,4>(bufA, wts + (size_t)i*262144, 512, wn, fm, fk8, h);
    add_bias<4>(bz + i*512, wn, fm, h);
    __syncthreads();                         // lin_z readers of bufA done
    write_relu<4>(bufA, l, wn, h);           // bufA = relu(h)
    __syncthreads();
    // fc0 in two n-halves: bufB = relu(relu(h) @ W0 + b0)
    #pragma unroll 1
    for (int half=0; half<2; ++half){
      f32x4 acc[4][2] = {};
      int nb = wn + half*32;
      gemm_any<16,2>(bufA, wts + (size_t)(5+i)*262144, 512, nb, fm, fk8, acc);
      add_bias<2>(b0 + i*512, nb, fm, acc);
      write_relu<2>(bufB, l, nb, acc);
    }
    __syncthreads();                         // fc0 writes visible; bufA readers done
    if (i < 4) stage_tile(bufA, alignedB + (size_t)m0*512, t);  // re-stage aligned
    // h += relu(net) @ W1 + b1  (bufB)
    gemm_any<16,4>(bufB, wts + (size_t)(10+i)*262144, 512, wn, fm, fk8, h);
    add_bias<4>(b1 + i*512, wn, fm, h);
    __syncthreads();                         // staging visible; bufB readers done
  }

  // sigma = exp(relu(h) . wout + bout)
  float s[4][4];
  #pragma unroll
  for (int mt=0;mt<4;mt++)
    #pragma unroll
    for (int r=0;r<4;r++){
      float a = 0.f;
      #pragma unroll
      for (int nt=0;nt<4;nt++)
        a += fmaxf(h[mt][nt][r], 0.f) * wout[wn + nt*16 + fm];
      s[mt][r] = a;
    }
  #pragma unroll
  for (int off=1; off<16; off<<=1)
    #pragma unroll
    for (int mt=0;mt<4;mt++)
      #pragma unroll
      for (int r=0;r<4;r++)
        s[mt][r] += __shfl_xor(s[mt][r], off, 64);
  float* red = (float*)bufB;       // bufB free (barrier above)
  if (fm == 0){
    int rq = (l>>4)*4;
    #pragma unroll
    for (int mt=0;mt<4;mt++)
      #pragma unroll
      for (int r=0;r<4;r++)
        red[w*64 + mt*16 + rq + r] = s[mt][r];
  }
  __syncthreads();
  if (t < 64){
    float a = bout[0];
    #pragma unroll
    for (int wv=0; wv<8; wv++) a += red[wv*64 + t];
    out[m0 + t] = expf(a);
  }
}

extern "C" void kernel_launch(void* const* d_in, const int* in_sizes, int n_in,
                              void* d_out, int out_size, void* d_ws, size_t ws_size,
                              hipStream_t stream) {
  const float* world = (const float*)d_in[0];
  const float* c2w   = (const float*)d_in[1];
  const float* kmat  = (const float*)d_in[2];
  const float* feat  = (const float*)d_in[3];
  const float* w_in  = (const float*)d_in[4];
  const float* b_in  = (const float*)d_in[5];
  const float* w_z   = (const float*)d_in[6];
  const float* b_z   = (const float*)d_in[7];
  const float* w_f0  = (const float*)d_in[8];
  const float* b_f0  = (const float*)d_in[9];
  const float* w_f1  = (const float*)d_in[10];
  const float* b_f1  = (const float*)d_in[11];
  const float* w_out = (const float*)d_in[12];
  const float* b_out = (const float*)d_in[13];
  float* out = (float*)d_out;
  char* ws = (char*)d_ws;

  size_t off = 0;
  u16* wts   = (u16*)(ws + off); off += (size_t)15*262144*2;       // 15x (512n x 512k) bf16
  u16* wtin  = (u16*)(ws + off); off += (size_t)512*64*2;          // (512n x 64k) bf16
  u16* featT = (u16*)(ws + off); off += (size_t)2*128*128*512*2;   // transposed features
  u16* alignedB = (u16*)(ws + off); off += (size_t)P_TOTAL*512*2;  // sampled features bf16
  u16* encB  = (u16*)(ws + off); off += (size_t)P_TOTAL*64*2;      // positional enc bf16

  k_wtrans15<<<dim3(16,16,15), 256, 0, stream>>>(w_z, w_f0, w_f1, wts);
  k_wtrans_in<<<dim3(2,16,1), 256, 0, stream>>>(w_in, wtin);
  k_featT<<<dim3(64,128,2), 128, 0, stream>>>(feat, featT);
  k_points<<<dim3(P_TOTAL/4), 256, 0, stream>>>(world, c2w, kmat, featT, alignedB, encB);
  k_net<<<dim3(P_TOTAL/64), 512, 0, stream>>>(alignedB, encB, wtin, b_in, wts,
      b_z, b_f0, b_f1, w_out, b_out, out);
}

// Round 8
// 1617.341 us; speedup vs baseline: 1.9690x; 1.9690x over previous
//
#include <hip/hip_runtime.h>

typedef __bf16 bf16_t;
typedef bf16_t bf16x8 __attribute__((ext_vector_type(8)));
typedef float f32x4 __attribute__((ext_vector_type(4)));
typedef unsigned short u16;

#define P_TOTAL 98304
#define PTS_PER_BATCH 49152
#define PITCH 520   // u16 elements per LDS row (1040 B = 65*16 -> banks vary with m)

__device__ __forceinline__ u16 f2bs(float f){ bf16_t b=(bf16_t)f; return __builtin_bit_cast(u16,b); }

// ---------- weight transpose: (K,N) fp32 -> (N,K) bf16 ----------
__global__ void k_wtrans15(const float* __restrict__ lz, const float* __restrict__ f0,
                           const float* __restrict__ f1, u16* __restrict__ dst){
  __shared__ float tile[32][33];
  int z = blockIdx.z;
  const float* src = (z<5) ? (lz + (size_t)z*262144)
                   : (z<10 ? (f0 + (size_t)(z-5)*262144)
                           : (f1 + (size_t)(z-10)*262144));
  u16* d = dst + (size_t)z*262144;
  int k0 = blockIdx.x*32, n0 = blockIdx.y*32;
  int t = threadIdx.x, a = t&31, r = t>>5;
  #pragma unroll
  for (int p=0;p<4;p++) tile[r+p*8][a] = src[(size_t)(k0+r+p*8)*512 + n0+a];
  __syncthreads();
  #pragma unroll
  for (int p=0;p<4;p++) d[(size_t)(n0+r+p*8)*512 + k0+a] = f2bs(tile[a][r+p*8]);
}

__global__ void k_wtrans_in(const float* __restrict__ w, u16* __restrict__ dst){
  __shared__ float tile[32][33];
  int k0 = blockIdx.x*32, n0 = blockIdx.y*32;
  int t = threadIdx.x, a = t&31, r = t>>5;
  #pragma unroll
  for (int p=0;p<4;p++){
    int k = k0+r+p*8;
    tile[r+p*8][a] = (k < 63) ? w[(size_t)k*512 + n0+a] : 0.f;
  }
  __syncthreads();
  #pragma unroll
  for (int p=0;p<4;p++) dst[(size_t)(n0+r+p*8)*64 + k0+a] = f2bs(tile[a][r+p*8]);
}

// ---------- feature transpose: (B,512,128,128) f32 -> (B,128,128,512) bf16 ----------
__global__ void k_featT(const float* __restrict__ feat, u16* __restrict__ featT){
  int x = threadIdx.x;
  int c8 = blockIdx.x*8;
  int y = blockIdx.y, b = blockIdx.z;
  float v[8];
  #pragma unroll
  for (int j=0;j<8;j++)
    v[j] = feat[(((size_t)(b*512 + c8 + j))*128 + y)*128 + x];
  bf16x8 o;
  #pragma unroll
  for (int j=0;j<8;j++) o[j] = (bf16_t)v[j];
  *(bf16x8*)(featT + (((size_t)(b*128 + y))*128 + x)*512 + c8) = o;
}

// ---------- per-point: geometry + bilinear + positional encoding ----------
__global__ void k_points(const float* __restrict__ world, const float* __restrict__ c2w,
                         const float* __restrict__ kmat, const u16* __restrict__ featT,
                         u16* __restrict__ alignedB, u16* __restrict__ encB){
  int wid = threadIdx.x >> 6, lane = threadIdx.x & 63;
  int gp = blockIdx.x*4 + wid;
  int b = gp / PTS_PER_BATCH;
  const float* wp = world + (size_t)gp*3;
  float px = wp[0], py = wp[1], pz = wp[2];
  const float* cw = c2w + b*16;
  float dx = px - cw[3], dy = py - cw[7], dz = pz - cw[11];
  float cx = cw[0]*dx + cw[4]*dy + cw[8]*dz;
  float cy = cw[1]*dx + cw[5]*dy + cw[9]*dz;
  float cz = cw[2]*dx + cw[6]*dy + cw[10]*dz;
  const float* km = kmat + b*9;
  float u0 = km[0]*cx + km[1]*cy + km[2]*cz;
  float v0 = km[3]*cx + km[4]*cy + km[5]*cz;
  float zz = km[6]*cx + km[7]*cy + km[8]*cz;
  if (fabsf(zz) < 1e-6f) zz = 1e-6f;
  float uu = u0/zz, vv = v0/zz;
  float xf = fminf(fmaxf(uu, 0.f), 127.f);
  float yf = fminf(fmaxf(vv, 0.f), 127.f);
  float x0f = floorf(xf), y0f = floorf(yf);
  int x0 = (int)x0f, y0 = (int)y0f;
  int x1 = min(x0+1,127), y1 = min(y0+1,127);
  float wx = xf - x0f, wy = yf - y0f;
  float w00 = (1.f-wx)*(1.f-wy), w01 = wx*(1.f-wy), w10 = (1.f-wx)*wy, w11 = wx*wy;
  size_t fb = (size_t)b*128*128*512;
  int c8 = lane*8;
  const bf16x8 t00 = *(const bf16x8*)(featT + fb + (size_t)(y0*128+x0)*512 + c8);
  const bf16x8 t01 = *(const bf16x8*)(featT + fb + (size_t)(y0*128+x1)*512 + c8);
  const bf16x8 t10 = *(const bf16x8*)(featT + fb + (size_t)(y1*128+x0)*512 + c8);
  const bf16x8 t11 = *(const bf16x8*)(featT + fb + (size_t)(y1*128+x1)*512 + c8);
  bf16x8 o;
  #pragma unroll
  for (int j=0;j<8;j++){
    float r = (float)t00[j]*w00 + (float)t01[j]*w01 + (float)t10[j]*w10 + (float)t11[j]*w11;
    o[j] = (bf16_t)r;
  }
  *(bf16x8*)(alignedB + (size_t)gp*512 + c8) = o;
  float cam[3] = {cx, cy, cz};
  float e;
  if (lane < 3) e = cam[lane];
  else if (lane < 33){
    int i = (lane-3)/10, f = (lane-3)%10;
    e = sinf(6.2831855f * cam[i] * (float)(1<<f));
  } else if (lane < 63){
    int i = (lane-33)/10, f = (lane-33)%10;
    e = cosf(6.2831855f * cam[i] * (float)(1<<f));
  } else e = 0.f;
  encB[(size_t)gp*64 + lane] = f2bs(e);
}

// ============ fused persistent MLP: 1024 thr (16 waves), M=64/block ============
// wave w owns n-strip [w*32, w*32+32) (NT=2). h fp32 resident: h[4][2] = 32 regs.
// Max live acc-class = h(32)+acc(32)=64; fits the 128-reg budget at 4 waves/SIMD.
// bufA = aligned (persistent, never clobbered), bufB = activations (rewritten 2x/layer).
// Weights (N,K) bf16 streamed from global (L2-broadcast), rolled 1-chunk reg dbuf.
// K-loop stays ROLLED (unroll 2 max) — full unroll => spill (round 4).

template<int NK>
__device__ __forceinline__ void gemm2(const u16* sA, const u16* __restrict__ Bt, int ldb,
                                      int n_base, int fm, int fk8, f32x4 (&acc)[4][2]){
  const u16* bp = Bt + (size_t)(n_base + fm)*ldb + fk8*8;
  bf16x8 b[2];
  #pragma unroll
  for (int nt=0;nt<2;nt++)
    b[nt] = *(const bf16x8*)(bp + nt*16*ldb);
  #pragma unroll 2
  for (int kt=0; kt<NK-1; ++kt){
    bf16x8 bn[2];
    #pragma unroll
    for (int nt=0;nt<2;nt++)
      bn[nt] = *(const bf16x8*)(bp + nt*16*ldb + (kt+1)*32);
    bf16x8 a[4];
    #pragma unroll
    for (int mt=0;mt<4;mt++){
      int m = mt*16 + fm;
      int kc = kt*4 + fk8;
      a[mt] = *(const bf16x8*)&sA[m*PITCH + kc*8];
    }
    #pragma unroll
    for (int mt=0;mt<4;mt++)
      #pragma unroll
      for (int nt=0;nt<2;nt++)
        acc[mt][nt] = __builtin_amdgcn_mfma_f32_16x16x32_bf16(a[mt], b[nt], acc[mt][nt], 0,0,0);
    #pragma unroll
    for (int nt=0;nt<2;nt++) b[nt] = bn[nt];
  }
  {
    bf16x8 a[4];
    #pragma unroll
    for (int mt=0;mt<4;mt++){
      int m = mt*16 + fm;
      int kc = (NK-1)*4 + fk8;
      a[mt] = *(const bf16x8*)&sA[m*PITCH + kc*8];
    }
    #pragma unroll
    for (int mt=0;mt<4;mt++)
      #pragma unroll
      for (int nt=0;nt<2;nt++)
        acc[mt][nt] = __builtin_amdgcn_mfma_f32_16x16x32_bf16(a[mt], b[nt], acc[mt][nt], 0,0,0);
  }
}

__device__ __forceinline__ void add_bias2(const float* __restrict__ bias, int n_base, int fm,
                                          f32x4 (&acc)[4][2]){
  #pragma unroll
  for (int nt=0;nt<2;nt++){
    float bv = bias[n_base + nt*16 + fm];
    #pragma unroll
    for (int mt=0;mt<4;mt++)
      #pragma unroll
      for (int r=0;r<4;r++) acc[mt][nt][r] += bv;
  }
}

// write relu(acc) bf16 into LDS cols [n_base, n_base+32) (C-layout -> A-layout)
__device__ __forceinline__ void write_relu2(u16* dst, int l, int n_base, f32x4 (&acc)[4][2]){
  const int fm = l&15, rq = (l>>4)*4;
  #pragma unroll
  for (int mt=0;mt<4;mt++)
    #pragma unroll
    for (int nt=0;nt<2;nt++){
      int k = n_base + nt*16 + fm;
      #pragma unroll
      for (int r=0;r<4;r++){
        int m = mt*16 + rq + r;
        dst[m*PITCH + k] = f2bs(fmaxf(acc[mt][nt][r], 0.f));
      }
    }
}

__global__ __launch_bounds__(1024, 4) void k_net(
    const u16* __restrict__ alignedB, const u16* __restrict__ encB,
    const u16* __restrict__ wtin, const float* __restrict__ b_in,
    const u16* __restrict__ wts, const float* __restrict__ bz,
    const float* __restrict__ b0, const float* __restrict__ b1,
    const float* __restrict__ wout, const float* __restrict__ bout,
    float* __restrict__ out)
{
  __shared__ u16 bufA[64*PITCH];   // aligned (65 KB, persistent)
  __shared__ u16 bufB[64*PITCH];   // activations (65 KB)
  const int t = threadIdx.x, w = t>>6, l = t&63;
  const int m0 = blockIdx.x*64;
  const int wn = w*32, fm = l&15, fk8 = l>>4;

  // stage aligned[m0:m0+64][0:512] -> bufA (1024 thr x 64 B = full 64x512 tile)
  {
    int m = t>>4, c = t&15;
    #pragma unroll
    for (int j=0;j<4;j++){
      int kc = c*4 + j;             // 0..63 -> covers all 512 columns
      *(uint4*)&bufA[m*PITCH + kc*8] =
          *(const uint4*)(alignedB + (size_t)(m0+m)*512 + kc*8);
    }
  }
  // stage enc[m0:m0+64][0:64] -> bufB (first 512 thr)
  if (t < 512){
    int m = t>>3, kc = t&7;
    *(uint4*)&bufB[m*PITCH + kc*8] =
        *(const uint4*)(encB + (size_t)(m0+m)*64 + kc*8);
  }
  __syncthreads();

  f32x4 h[4][2] = {};
  gemm2<2>(bufB, wtin, 64, wn, fm, fk8, h);
  add_bias2(b_in, wn, fm, h);

  #pragma unroll 1
  for (int i=0;i<5;i++){
    // h += aligned @ Wz + bz   (bufA)
    gemm2<16>(bufA, wts + (size_t)i*262144, 512, wn, fm, fk8, h);
    add_bias2(bz + i*512, wn, fm, h);
    __syncthreads();                       // prior bufB readers done
    write_relu2(bufB, l, wn, h);           // bufB = relu(h)
    __syncthreads();
    f32x4 acc[4][2] = {};
    gemm2<16>(bufB, wts + (size_t)(5+i)*262144, 512, wn, fm, fk8, acc);
    add_bias2(b0 + i*512, wn, fm, acc);
    __syncthreads();                       // all fc0 reads of bufB done
    write_relu2(bufB, l, wn, acc);         // bufB = relu(net)
    __syncthreads();
    gemm2<16>(bufB, wts + (size_t)(10+i)*262144, 512, wn, fm, fk8, h);
    add_bias2(b1 + i*512, wn, fm, h);
  }

  // sigma = exp(relu(h) . wout + bout)
  float s[4][4];
  #pragma unroll
  for (int mt=0;mt<4;mt++)
    #pragma unroll
    for (int r=0;r<4;r++){
      float a = 0.f;
      #pragma unroll
      for (int nt=0;nt<2;nt++)
        a += fmaxf(h[mt][nt][r], 0.f) * wout[wn + nt*16 + fm];
      s[mt][r] = a;
    }
  #pragma unroll
  for (int off=1; off<16; off<<=1)
    #pragma unroll
    for (int mt=0;mt<4;mt++)
      #pragma unroll
      for (int r=0;r<4;r++)
        s[mt][r] += __shfl_xor(s[mt][r], off, 64);
  __syncthreads();                 // all fc1 reads of bufB done; reuse as red[16][64]
  float* red = (float*)bufB;
  if (fm == 0){
    int rq = (l>>4)*4;
    #pragma unroll
    for (int mt=0;mt<4;mt++)
      #pragma unroll
      for (int r=0;r<4;r++)
        red[w*64 + mt*16 + rq + r] = s[mt][r];
  }
  __syncthreads();
  if (t < 64){
    float a = bout[0];
    #pragma unroll
    for (int wv=0; wv<16; wv++) a += red[wv*64 + t];
    out[m0 + t] = expf(a);
  }
}

extern "C" void kernel_launch(void* const* d_in, const int* in_sizes, int n_in,
                              void* d_out, int out_size, void* d_ws, size_t ws_size,
                              hipStream_t stream) {
  const float* world = (const float*)d_in[0];
  const float* c2w   = (const float*)d_in[1];
  const float* kmat  = (const float*)d_in[2];
  const float* feat  = (const float*)d_in[3];
  const float* w_in  = (const float*)d_in[4];
  const float* b_in  = (const float*)d_in[5];
  const float* w_z   = (const float*)d_in[6];
  const float* b_z   = (const float*)d_in[7];
  const float* w_f0  = (const float*)d_in[8];
  const float* b_f0  = (const float*)d_in[9];
  const float* w_f1  = (const float*)d_in[10];
  const float* b_f1  = (const float*)d_in[11];
  const float* w_out = (const float*)d_in[12];
  const float* b_out = (const float*)d_in[13];
  float* out = (float*)d_out;
  char* ws = (char*)d_ws;

  size_t off = 0;
  u16* wts   = (u16*)(ws + off); off += (size_t)15*262144*2;       // 15x (512n x 512k) bf16
  u16* wtin  = (u16*)(ws + off); off += (size_t)512*64*2;          // (512n x 64k) bf16
  u16* featT = (u16*)(ws + off); off += (size_t)2*128*128*512*2;   // transposed features
  u16* alignedB = (u16*)(ws + off); off += (size_t)P_TOTAL*512*2;  // sampled features bf16
  u16* encB  = (u16*)(ws + off); off += (size_t)P_TOTAL*64*2;      // positional enc bf16

  k_wtrans15<<<dim3(16,16,15), 256, 0, stream>>>(w_z, w_f0, w_f1, wts);
  k_wtrans_in<<<dim3(2,16,1), 256, 0, stream>>>(w_in, wtin);
  k_featT<<<dim3(64,128,2), 128, 0, stream>>>(feat, featT);
  k_points<<<dim3(P_TOTAL/4), 256, 0, stream>>>(world, c2w, kmat, featT, alignedB, encB);
  k_net<<<dim3(P_TOTAL/64), 1024, 0, stream>>>(alignedB, encB, wtin, b_in, wts,
      b_z, b_f0, b_f1, w_out, b_out, out);
}